// Round 17
// baseline (845.465 us; speedup 1.0000x reference)
//
#include <hip/hip_runtime.h>
#include <type_traits>

// ---------------------------------------------------------------------------
// CSAAttention — round 17 = round 16 + WIDER f64 TILE (64x128, wave 32x64):
//   MFMA density per quad 4->8 (reads 6 per 8 MFMAs), B-panel loads halved.
//   Per-accumulator ascending-k chains unchanged -> bit-identical;
//   absmax must stay exactly 0.00390625. Value path / topk / kn: R16 verbatim.
// ---------------------------------------------------------------------------

#define DEVI __device__ __forceinline__

constexpr int Tn = 1024;
constexpr int Cn = 1024;
constexpr int Hn = 16;

typedef short bf16x8 __attribute__((ext_vector_type(8)));
typedef float f32x4 __attribute__((ext_vector_type(4)));
typedef double f64x4 __attribute__((ext_vector_type(4)));

DEVI int wsumi(int v)   { for (int m = 1; m < 64; m <<= 1) v += __shfl_xor(v, m); return v; }
DEVI int wmini(int v)   { for (int m = 1; m < 64; m <<= 1) { int o = __shfl_xor(v, m); v = o < v ? o : v; } return v; }
DEVI float wfmax(float v){ for (int m = 1; m < 64; m <<= 1) v = fmaxf(v, __shfl_xor(v, m)); return v; }
DEVI float wfsum(float v){ for (int m = 1; m < 64; m <<= 1) v += __shfl_xor(v, m); return v; }

DEVI unsigned long long mapd(double x) {  // monotone fp64 -> uint64
  unsigned long long b = (unsigned long long)__double_as_longlong(x);
  return (b >> 63) ? ~b : (b | 0x8000000000000000ull);
}

DEVI unsigned short f2bf_rne(float x) {
  unsigned u = __float_as_uint(x);
  u += 0x7fffu + ((u >> 16) & 1u);
  return (unsigned short)(u >> 16);
}
struct BfPair { short hi, lo; };
DEVI BfPair split2(float x) {
  unsigned short h = f2bf_rne(x);
  float hf = __uint_as_float(((unsigned)h) << 16);
  BfPair r;
  r.hi = (short)h;
  r.lo = (short)f2bf_rne(x - hf);
  return r;
}

// ---------------------------------------------------------------------------
// Selection-path fp64 GEMM, probed f64-MFMA, tile 64(M)x128(N), BK=32,
// double-buffered LDS. Wave tile 32x64 (acc 2x4). MODE: 0 = z-batch,
// 1 = SIM (dot planes), 2 = DUAL (z picks {B,bias,C} vs {Bx,biasx,Cx}).
// Per-acc ascending-k chains -> bit-identical to R12-R16.
// ---------------------------------------------------------------------------
template <typename OUTT, bool BTRANS, int BIASMODE, int MODE>
__global__ __launch_bounds__(256) void f64sel_k(
    const float* __restrict__ A, const float* __restrict__ B,
    const float* __restrict__ Bx, const float* __restrict__ bias,
    const float* __restrict__ biasx, OUTT* __restrict__ C, OUTT* __restrict__ Cx,
    int Kd, int lda, int ldb, int ldc,
    long long zB, long long zC, int group_base)
{
  __shared__ float As[2][32][72];    // [k][m], m<64
  __shared__ float Bs[2][32][136];   // [k][n], n<128

  const float* Ab = A;
  const float* Bb = B;
  OUTT* Cb = C;
  if (MODE == 1) {
    int pair = group_base + (int)blockIdx.z;
    int bb = pair >> 4, hh = pair & 15;
    Ab = A + ((size_t)bb * Tn) * (size_t)lda + (size_t)hh * 64;
    Bb = B + ((size_t)bb * Cn) * (size_t)ldb + (size_t)hh * 64;
    Cb = C + (size_t)blockIdx.z * (size_t)Tn * (size_t)ldc;
  } else if (MODE == 0) {
    Bb = B + (size_t)blockIdx.z * (size_t)zB;
    Cb = C + (size_t)blockIdx.z * (size_t)zC;
  } else {  // DUAL
    if (blockIdx.z == 1) { Bb = Bx; bias = biasx; Cb = Cx; }
  }

  const int tid = threadIdx.x;
  const int lane = tid & 63, w = tid >> 6;
  const int wr = w >> 1, wc = w & 1;
  const int l15 = lane & 15, l4 = lane >> 4;
  const int m0 = blockIdx.y * 64, n0 = blockIdx.x * 128;

  // runtime layout probe (wave-uniform) — R12-validated
  f64x4 zz = {0.0, 0.0, 0.0, 0.0};
  f64x4 p1 = __builtin_amdgcn_mfma_f64_16x16x4f64(1.0, (double)l15, zz, 0, 0, 0);
  f64x4 p2 = __builtin_amdgcn_mfma_f64_16x16x4f64((double)l15, 1.0, zz, 0, 0, 0);
  int a1 = 1, b1 = 1, c1 = 1, a2 = 1, b2 = 1, c2 = 1;
#pragma unroll
  for (int rr = 0; rr < 4; ++rr) {
    a1 &= (p1[rr] == 4.0 * l15);
    b1 &= (p1[rr] == 4.0 * (l4 * 4 + rr));
    c1 &= (p1[rr] == 4.0 * (l4 + 4 * rr));
    a2 &= (p2[rr] == 4.0 * (l4 * 4 + rr));
    b2 &= (p2[rr] == 4.0 * (l4 + 4 * rr));
    c2 &= (p2[rr] == 4.0 * l15);
  }
  a1 = __all(a1); b1 = __all(b1); c1 = __all(c1);
  a2 = __all(a2); b2 = __all(b2); c2 = __all(c2);
  int dmap = 0, useM = 1;
  if      (a1 && a2) dmap = 0;
  else if (a1 && b2) dmap = 1;
  else if (b1 && c2) dmap = 2;
  else if (c1 && c2) dmap = 3;
  else useM = 0;

  f64x4 acc[2][4];
#pragma unroll
  for (int i = 0; i < 2; ++i)
#pragma unroll
    for (int j = 0; j < 4; ++j) acc[i][j] = (f64x4){0.0, 0.0, 0.0, 0.0};

  // staging indices
  const int am = tid >> 2, akf = tid & 3;           // A rows (64)
  const int btn = tid >> 1, btkh = (tid & 1) * 16;  // B-trans rows (128)
  const int bkk = tid >> 3, bnf = (tid & 7) * 16;   // B non-trans (32k x 128n)

  const int nT = Kd >> 5;
  float4 a0_, a1_, b0_, b1_, b2_, b3_;

  auto LOADT = [&](int k0) {
    a0_ = *(const float4*)(Ab + (size_t)(m0 + am) * lda + k0 + 4 * akf);
    a1_ = *(const float4*)(Ab + (size_t)(m0 + am) * lda + k0 + 16 + 4 * akf);
    if (BTRANS) {
      const float* p = Bb + (size_t)(n0 + btn) * ldb + k0 + btkh;
      b0_ = *(const float4*)(p + 0);
      b1_ = *(const float4*)(p + 4);
      b2_ = *(const float4*)(p + 8);
      b3_ = *(const float4*)(p + 12);
    } else {
      const float* p = Bb + (size_t)(k0 + bkk) * ldb + n0 + bnf;
      b0_ = *(const float4*)(p + 0);
      b1_ = *(const float4*)(p + 4);
      b2_ = *(const float4*)(p + 8);
      b3_ = *(const float4*)(p + 12);
    }
  };
  auto WRITET = [&](int buf) {
    As[buf][4 * akf + 0][am] = a0_.x; As[buf][4 * akf + 1][am] = a0_.y;
    As[buf][4 * akf + 2][am] = a0_.z; As[buf][4 * akf + 3][am] = a0_.w;
    As[buf][16 + 4 * akf + 0][am] = a1_.x; As[buf][16 + 4 * akf + 1][am] = a1_.y;
    As[buf][16 + 4 * akf + 2][am] = a1_.z; As[buf][16 + 4 * akf + 3][am] = a1_.w;
    if (BTRANS) {
      Bs[buf][btkh + 0][btn] = b0_.x;  Bs[buf][btkh + 1][btn] = b0_.y;
      Bs[buf][btkh + 2][btn] = b0_.z;  Bs[buf][btkh + 3][btn] = b0_.w;
      Bs[buf][btkh + 4][btn] = b1_.x;  Bs[buf][btkh + 5][btn] = b1_.y;
      Bs[buf][btkh + 6][btn] = b1_.z;  Bs[buf][btkh + 7][btn] = b1_.w;
      Bs[buf][btkh + 8][btn] = b2_.x;  Bs[buf][btkh + 9][btn] = b2_.y;
      Bs[buf][btkh + 10][btn] = b2_.z; Bs[buf][btkh + 11][btn] = b2_.w;
      Bs[buf][btkh + 12][btn] = b3_.x; Bs[buf][btkh + 13][btn] = b3_.y;
      Bs[buf][btkh + 14][btn] = b3_.z; Bs[buf][btkh + 15][btn] = b3_.w;
    } else {
      *(float4*)&Bs[buf][bkk][bnf + 0]  = b0_;
      *(float4*)&Bs[buf][bkk][bnf + 4]  = b1_;
      *(float4*)&Bs[buf][bkk][bnf + 8]  = b2_;
      *(float4*)&Bs[buf][bkk][bnf + 12] = b3_;
    }
  };

  LOADT(0);
  WRITET(0);
  __syncthreads();

  for (int kt = 0; kt < nT; ++kt) {
    const int cur = kt & 1;
    if (kt + 1 < nT) LOADT((kt + 1) * 32);   // issue loads (overlap MFMA)

    if (useM) {
#pragma unroll
      for (int kq = 0; kq < 8; ++kq) {
        int kk = kq * 4 + l4;
        double a0  = (double)As[cur][kk][wr * 32 + l15];
        double a1v = (double)As[cur][kk][wr * 32 + 16 + l15];
        double bb0 = (double)Bs[cur][kk][wc * 64 + l15];
        double bb1 = (double)Bs[cur][kk][wc * 64 + 16 + l15];
        double bb2 = (double)Bs[cur][kk][wc * 64 + 32 + l15];
        double bb3 = (double)Bs[cur][kk][wc * 64 + 48 + l15];
        acc[0][0] = __builtin_amdgcn_mfma_f64_16x16x4f64(a0,  bb0, acc[0][0], 0, 0, 0);
        acc[0][1] = __builtin_amdgcn_mfma_f64_16x16x4f64(a0,  bb1, acc[0][1], 0, 0, 0);
        acc[0][2] = __builtin_amdgcn_mfma_f64_16x16x4f64(a0,  bb2, acc[0][2], 0, 0, 0);
        acc[0][3] = __builtin_amdgcn_mfma_f64_16x16x4f64(a0,  bb3, acc[0][3], 0, 0, 0);
        acc[1][0] = __builtin_amdgcn_mfma_f64_16x16x4f64(a1v, bb0, acc[1][0], 0, 0, 0);
        acc[1][1] = __builtin_amdgcn_mfma_f64_16x16x4f64(a1v, bb1, acc[1][1], 0, 0, 0);
        acc[1][2] = __builtin_amdgcn_mfma_f64_16x16x4f64(a1v, bb2, acc[1][2], 0, 0, 0);
        acc[1][3] = __builtin_amdgcn_mfma_f64_16x16x4f64(a1v, bb3, acc[1][3], 0, 0, 0);
      }
    } else {
#pragma unroll
      for (int k = 0; k < 32; ++k) {
        double bv[4];
#pragma unroll
        for (int fc = 0; fc < 4; ++fc)
          bv[fc] = (double)Bs[cur][k][wc * 64 + fc * 16 + l15];
#pragma unroll
        for (int fr = 0; fr < 2; ++fr)
#pragma unroll
          for (int rr = 0; rr < 4; ++rr) {
            double av = (double)As[cur][k][wr * 32 + fr * 16 + l4 * 4 + rr];
#pragma unroll
            for (int fc = 0; fc < 4; ++fc)
              acc[fr][fc][rr] += av * bv[fc];
          }
      }
    }

    if (kt + 1 < nT) WRITET(cur ^ 1);
    __syncthreads();
  }

  // epilogue (frozen formula: fp64->fp32 cast, then fp32 bias adds)
#pragma unroll
  for (int fr = 0; fr < 2; ++fr)
#pragma unroll
    for (int fc = 0; fc < 4; ++fc)
#pragma unroll
      for (int rr = 0; rr < 4; ++rr) {
        int ri, ci;
        if (!useM || dmap == 0) { ri = l4 * 4 + rr; ci = l15; }
        else if (dmap == 1)     { ri = l4 + 4 * rr; ci = l15; }
        else if (dmap == 2)     { ri = l15; ci = l4 * 4 + rr; }
        else                    { ri = l15; ci = l4 + 4 * rr; }
        int row = m0 + wr * 32 + fr * 16 + ri;
        int col = n0 + wc * 64 + fc * 16 + ci;
        double v = acc[fr][fc][rr];
        if constexpr (std::is_same<OUTT, double>::value) {
          Cb[(size_t)row * ldc + col] = v;
        } else {
          float s = (float)v;
          float cb = (BIASMODE == 1) ? bias[col] : 0.f;
          float rb = (BIASMODE == 2) ? bias[row] : 0.f;
          ((float*)Cb)[(size_t)row * ldc + col] = s + cb + rb;
        }
      }
}

// ---------------------------------------------------------------------------
// Value-path MFMA GEMM, double-buffered LDS (R16 verbatim; bit-identical).
// ---------------------------------------------------------------------------
template <bool BTRANS, int BIASMODE>
__global__ __launch_bounds__(256) void mfma_gemm_k(
    const float* __restrict__ A, const float* __restrict__ B,
    const float* __restrict__ bias, float* __restrict__ C,
    int Kd, int lda, int ldb, int ldc, long long zB, long long zC)
{
  __shared__ short Ah[2][4 * 64 * 8];
  __shared__ short Al[2][4 * 64 * 8];
  __shared__ short Bh[2][4 * 64 * 8];
  __shared__ short Bl[2][4 * 64 * 8];

  const float* Bz = B + (size_t)blockIdx.z * (size_t)zB;
  float* Cz = C + (size_t)blockIdx.z * (size_t)zC;

  const int tid = threadIdx.x;
  const int lane = tid & 63, w = tid >> 6;
  const int wr = w >> 1, wc = w & 1;
  const int m0 = blockIdx.y * 64, n0 = blockIdx.x * 64;
  const int r16 = lane & 15, kg = lane >> 4;

  f32x4 acc[2][2];
#pragma unroll
  for (int i = 0; i < 2; ++i)
#pragma unroll
    for (int j = 0; j < 2; ++j) acc[i][j] = (f32x4){0.f, 0.f, 0.f, 0.f};

  const int row = tid >> 2, kseg = tid & 3;
  const int gcol = tid & 63, gks = tid >> 6;

  const int nT = Kd >> 5;
  float4 pa0, pa1, pb0, pb1;
  float gb[8];

  auto LOADT = [&](int k0) {
    pa0 = *(const float4*)(A + (size_t)(m0 + row) * lda + k0 + kseg * 8);
    pa1 = *(const float4*)(A + (size_t)(m0 + row) * lda + k0 + kseg * 8 + 4);
    if (BTRANS) {
      pb0 = *(const float4*)(Bz + (size_t)(n0 + row) * ldb + k0 + kseg * 8);
      pb1 = *(const float4*)(Bz + (size_t)(n0 + row) * ldb + k0 + kseg * 8 + 4);
    } else {
#pragma unroll
      for (int j = 0; j < 8; ++j)
        gb[j] = Bz[(size_t)(k0 + gks * 8 + j) * ldb + n0 + gcol];
    }
  };
  auto WRITET = [&](int buf) {
    {
      BfPair q0 = split2(pa0.x), q1 = split2(pa0.y), q2 = split2(pa0.z), q3 = split2(pa0.w);
      BfPair q4 = split2(pa1.x), q5 = split2(pa1.y), q6 = split2(pa1.z), q7 = split2(pa1.w);
      bf16x8 h = {q0.hi, q1.hi, q2.hi, q3.hi, q4.hi, q5.hi, q6.hi, q7.hi};
      bf16x8 l = {q0.lo, q1.lo, q2.lo, q3.lo, q4.lo, q5.lo, q6.lo, q7.lo};
      int idx = (kseg * 64 + row) * 8;
      *(bf16x8*)&Ah[buf][idx] = h;
      *(bf16x8*)&Al[buf][idx] = l;
    }
    if (BTRANS) {
      BfPair q0 = split2(pb0.x), q1 = split2(pb0.y), q2 = split2(pb0.z), q3 = split2(pb0.w);
      BfPair q4 = split2(pb1.x), q5 = split2(pb1.y), q6 = split2(pb1.z), q7 = split2(pb1.w);
      bf16x8 h = {q0.hi, q1.hi, q2.hi, q3.hi, q4.hi, q5.hi, q6.hi, q7.hi};
      bf16x8 l = {q0.lo, q1.lo, q2.lo, q3.lo, q4.lo, q5.lo, q6.lo, q7.lo};
      int idx = (kseg * 64 + row) * 8;
      *(bf16x8*)&Bh[buf][idx] = h;
      *(bf16x8*)&Bl[buf][idx] = l;
    } else {
      short hv[8], lv[8];
#pragma unroll
      for (int j = 0; j < 8; ++j) {
        BfPair p = split2(gb[j]);
        hv[j] = p.hi; lv[j] = p.lo;
      }
      bf16x8 h = {hv[0], hv[1], hv[2], hv[3], hv[4], hv[5], hv[6], hv[7]};
      bf16x8 l = {lv[0], lv[1], lv[2], lv[3], lv[4], lv[5], lv[6], lv[7]};
      int idx = (gks * 64 + gcol) * 8;
      *(bf16x8*)&Bh[buf][idx] = h;
      *(bf16x8*)&Bl[buf][idx] = l;
    }
  };

  LOADT(0);
  WRITET(0);
  __syncthreads();

  for (int kt = 0; kt < nT; ++kt) {
    const int cur = kt & 1;
    if (kt + 1 < nT) LOADT((kt + 1) * 32);

    bf16x8 ah[2], al[2], bh[2], bl[2];
#pragma unroll
    for (int f = 0; f < 2; ++f) {
      int ia = (kg * 64 + wr * 32 + f * 16 + r16) * 8;
      int ib = (kg * 64 + wc * 32 + f * 16 + r16) * 8;
      ah[f] = *(const bf16x8*)&Ah[cur][ia];
      al[f] = *(const bf16x8*)&Al[cur][ia];
      bh[f] = *(const bf16x8*)&Bh[cur][ib];
      bl[f] = *(const bf16x8*)&Bl[cur][ib];
    }
#pragma unroll
    for (int fr = 0; fr < 2; ++fr)
#pragma unroll
      for (int fc = 0; fc < 2; ++fc) {
        f32x4 c = acc[fr][fc];
        c = __builtin_amdgcn_mfma_f32_16x16x32_bf16(al[fr], bh[fc], c, 0, 0, 0);
        c = __builtin_amdgcn_mfma_f32_16x16x32_bf16(ah[fr], bl[fc], c, 0, 0, 0);
        c = __builtin_amdgcn_mfma_f32_16x16x32_bf16(ah[fr], bh[fc], c, 0, 0, 0);
        acc[fr][fc] = c;
      }

    if (kt + 1 < nT) WRITET(cur ^ 1);
    __syncthreads();
  }

#pragma unroll
  for (int fr = 0; fr < 2; ++fr)
#pragma unroll
    for (int fc = 0; fc < 2; ++fc) {
      int col = n0 + wc * 32 + fc * 16 + r16;
      float cb = (BIASMODE == 1) ? bias[col] : 0.f;
#pragma unroll
      for (int rr = 0; rr < 4; ++rr) {
        int rw = m0 + wr * 32 + fr * 16 + kg * 4 + rr;
        float rb = (BIASMODE == 2) ? bias[rw] : 0.f;
        Cz[(size_t)rw * ldc + col] = acc[fr][fc][rr] + cb + rb;
      }
    }
}

// kn[b*16+h][c] = 1 / max(||Kc[b, c, h*64 : +64]||, 1e-12)   (fp64)
__global__ __launch_bounds__(256) void kn_k2(const float* __restrict__ Kc,
                                             double* __restrict__ kn)
{
  int idx = (int)blockIdx.x * 256 + (int)threadIdx.x;
  int c = idx & 1023;
  int p = idx >> 10;
  int b = p >> 4, h = p & 15;
  const float* row = Kc + ((size_t)(b * 1024 + c)) * 1024 + h * 64;
  double s = 0.0;
  for (int d = 0; d < 64; ++d) { double v = (double)row[d]; s += v * v; }
  kn[(size_t)p * 1024 + c] = 1.0 / fmax(sqrt(s), 1e-12);
}

// Fused exact top-64 + softmax + PV (bit-frozen, R5-validated).
__global__ __launch_bounds__(256) void topk_attn_k(
    const double* __restrict__ dotb, const double* __restrict__ kn,
    const float* __restrict__ Vc, float* __restrict__ attnout, int group_base)
{
  __shared__ int sC[4][64];
  __shared__ float sD[4][64];

  const int lane = threadIdx.x & 63, wv = threadIdx.x >> 6;
  const int g = (int)blockIdx.x >> 8;
  const int t = ((int)blockIdx.x & 255) * 4 + wv;
  const int pair = group_base + g;
  const int bb = pair >> 4, hh = pair & 15;

  const double* drow = dotb + ((size_t)g * Tn + t) * (size_t)Cn;
  const double* knr  = kn + ((size_t)(bb * Hn + hh)) * Cn;

  double dv[16];
  unsigned long long u[16];
#pragma unroll
  for (int j = 0; j < 8; ++j) {
    double2 dd = *(const double2*)(drow + j * 128 + 2 * lane);
    double2 kk = *(const double2*)(knr  + j * 128 + 2 * lane);
    dv[2 * j] = dd.x; dv[2 * j + 1] = dd.y;
    u[2 * j]     = mapd(dd.x * kk.x);
    u[2 * j + 1] = mapd(dd.y * kk.y);
  }
  unsigned hi[16];
#pragma unroll
  for (int i = 0; i < 16; ++i) hi[i] = (unsigned)(u[i] >> 32);

  unsigned TH = 0;
  for (int bit = 31; bit >= 0; --bit) {
    unsigned Tc = TH | (1u << bit);
    int c = 0;
#pragma unroll
    for (int i = 0; i < 16; ++i) c += (hi[i] >= Tc);
    if (wsumi(c) >= 64) TH = Tc;
  }
  int mhi = 0;
#pragma unroll
  for (int i = 0; i < 16; ++i) mhi += (hi[i] > TH);
  mhi = wsumi(mhi);
  const int need1 = 64 - mhi;
  unsigned TL = 0;
  for (int bit = 31; bit >= 0; --bit) {
    unsigned Tc = TL | (1u << bit);
    int c = 0;
#pragma unroll
    for (int i = 0; i < 16; ++i) c += (hi[i] == TH && (unsigned)u[i] >= Tc);
    if (wsumi(c) >= need1) TL = Tc;
  }
  const unsigned long long V64 = ((unsigned long long)TH << 32) | TL;

  int base = 0;
#pragma unroll
  for (int i = 0; i < 16; ++i) {
    const int cix = 128 * (i >> 1) + 2 * lane + (i & 1);
    bool sel = (u[i] > V64);
    unsigned long long mk = __ballot(sel);
    if (sel) {
      int r = __popcll(mk & ((1ull << lane) - 1ull));
      sC[wv][base + r] = cix;
      sD[wv][base + r] = (float)dv[i];
    }
    base += __popcll(mk);
  }
  const int need = 64 - base;
  unsigned taken = 0;
  for (int r = 0; r < need; ++r) {
    int mn = 0x7fffffff;
#pragma unroll
    for (int i = 0; i < 16; ++i) {
      int cix = 128 * (i >> 1) + 2 * lane + (i & 1);
      if (u[i] == V64 && !((taken >> i) & 1u)) mn = mn < cix ? mn : cix;
    }
    mn = wmini(mn);
#pragma unroll
    for (int i = 0; i < 16; ++i) {
      int cix = 128 * (i >> 1) + 2 * lane + (i & 1);
      if (u[i] == V64 && !((taken >> i) & 1u) && cix == mn) {
        taken |= 1u << i;
        sC[wv][base + r] = mn;
        sD[wv][base + r] = (float)dv[i];
      }
    }
  }
  __syncthreads();

  int ck = sC[wv][lane];
  float sc = sD[wv][lane] * 0.125f;
  float mx = wfmax(sc);
  float w = expf(sc - mx);
  float sw = wfsum(w);
  w /= sw;

  const float* Vb = Vc + (size_t)bb * ((size_t)Cn * 1024) + hh * 64 + lane;
  float acc = 0.f;
#pragma unroll 4
  for (int k = 0; k < 64; ++k) {
    int c = __shfl(ck, k);
    float wk = __shfl(w, k);
    acc = fmaf(wk, Vb[(size_t)c * 1024], acc);
  }
  attnout[((size_t)(bb * Tn + t)) * 1024 + hh * 64 + lane] = acc;
}

// ---------------------------------------------------------------------------
extern "C" void kernel_launch(void* const* d_in, const int* in_sizes, int n_in,
                              void* d_out, int out_size, void* d_ws, size_t ws_size,
                              hipStream_t stream)
{
  const float* x  = (const float*)d_in[0];
  const float* Wq = (const float*)d_in[1];
  const float* bq = (const float*)d_in[2];
  const float* Wk = (const float*)d_in[3];
  const float* bk = (const float*)d_in[4];
  const float* Wv = (const float*)d_in[5];
  const float* bv = (const float*)d_in[6];
  const float* Wo = (const float*)d_in[7];
  const float* bo = (const float*)d_in[8];
  const float* Wc = (const float*)d_in[9];
  const float* bc = (const float*)d_in[10];
  float* out = (float*)d_out;

  const size_t NE = (size_t)2048 * 1024;
  const size_t M1 = (size_t)1024 * 1024;
  float* Q   = (float*)d_ws;
  float* Kf  = Q + NE;
  float* Vf  = Kf + NE;
  float* Kc  = Vf + NE;
  float* Vc  = Kc + NE;
  float* at  = Vc + NE;
  double* kn = (double*)(at + NE);
  double* tail = kn + 32768;

  const size_t fixedB = 6 * NE * 4 + 32768 * 8;
  const size_t dotPairB = (size_t)Tn * Cn * 8;   // 8 MiB per (b,h) pair
  if (ws_size < fixedB) return;

  size_t rem = ws_size - fixedB;
  double* dotp; int G;
  if      (rem >= 32 * dotPairB) { G = 32; dotp = tail; }
  else if (rem >= 16 * dotPairB) { G = 16; dotp = tail; }
  else if (rem >=  8 * dotPairB) { G = 8;  dotp = tail; }
  else if (rem >=  4 * dotPairB) { G = 4;  dotp = tail; }
  else if (rem >=  2 * dotPairB) { G = 2;  dotp = tail; }
  else { G = 2; dotp = (double*)Kf; }  // Kf+Vf dead by then (16 MiB)

  dim3 blk(256, 1, 1);

  // Q + K projections merged (DUAL, 64x128 tile): grid (8, 32, 2)
  f64sel_k<float, true, 1, 2><<<dim3(8, 32, 2), blk, 0, stream>>>(
      x, Wq, Wk, bq, bk, Q, Kf, 1024, 1024, 1024, 1024, 0, 0, 0);
  // Value-path V projection (dbuf)
  mfma_gemm_k<true, 1><<<dim3(16, 32, 1), blk, 0, stream>>>(
      x, Wv, bv, Vf, 1024, 1024, 1024, 1024, 0, 0);

  // Compress: Kc (f64-MFMA, 64x128): grid (8, 16, 2); Vc (value MFMA)
  f64sel_k<float, false, 2, 0><<<dim3(8, 16, 2), blk, 0, stream>>>(
      Wc, Kf, nullptr, bc, nullptr, Kc, nullptr,
      1024, 1024, 1024, 1024, (long long)M1, (long long)M1, 0);
  mfma_gemm_k<false, 2><<<dim3(16, 16, 2), blk, 0, stream>>>(
      Wc, Vf, bc, Vc, 1024, 1024, 1024, 1024, (long long)M1, (long long)M1);

  kn_k2<<<dim3(128), blk, 0, stream>>>(Kc, kn);

  // Dot planes (f64-MFMA SIM, 64x128) + fused topk/softmax/PV
  for (int gb = 0; gb < 32; gb += G) {
    f64sel_k<double, true, 0, 1><<<dim3(8, 16, G), blk, 0, stream>>>(
        Q, Kc, nullptr, nullptr, nullptr, dotp, nullptr,
        64, 1024, 1024, 1024, 0, 0, gb);
    topk_attn_k<<<dim3(256 * G), blk, 0, stream>>>(dotp, kn, Vc, at, gb);
  }

  // Output projection (dbuf)
  mfma_gemm_k<true, 1><<<dim3(16, 32, 1), blk, 0, stream>>>(
      at, Wo, bo, out, 1024, 1024, 1024, 1024, 0, 0);
}

// Round 18
// 809.440 us; speedup vs baseline: 1.0445x; 1.0445x over previous
//
#include <hip/hip_runtime.h>
#include <type_traits>

// ---------------------------------------------------------------------------
// CSAAttention — round 18 = round 16 (812us best; 64x64 f64 tile reverted)
//   + HETEROGENEOUS FUSED DISPATCHES: independent f64-selection and bf16-value
//   GEMMs merged into single launches (blockIdx.z picks the body) so the
//   value path fills the f64 pipe's idle cycles. All code paths bit-identical
//   to R16 -> absmax must stay exactly 0.00390625.
// ---------------------------------------------------------------------------

#define DEVI __device__ __forceinline__

constexpr int Tn = 1024;
constexpr int Cn = 1024;
constexpr int Hn = 16;

typedef short bf16x8 __attribute__((ext_vector_type(8)));
typedef float f32x4 __attribute__((ext_vector_type(4)));
typedef double f64x4 __attribute__((ext_vector_type(4)));

DEVI int wsumi(int v)   { for (int m = 1; m < 64; m <<= 1) v += __shfl_xor(v, m); return v; }
DEVI int wmini(int v)   { for (int m = 1; m < 64; m <<= 1) { int o = __shfl_xor(v, m); v = o < v ? o : v; } return v; }
DEVI float wfmax(float v){ for (int m = 1; m < 64; m <<= 1) v = fmaxf(v, __shfl_xor(v, m)); return v; }
DEVI float wfsum(float v){ for (int m = 1; m < 64; m <<= 1) v += __shfl_xor(v, m); return v; }

DEVI unsigned long long mapd(double x) {  // monotone fp64 -> uint64
  unsigned long long b = (unsigned long long)__double_as_longlong(x);
  return (b >> 63) ? ~b : (b | 0x8000000000000000ull);
}

DEVI unsigned short f2bf_rne(float x) {
  unsigned u = __float_as_uint(x);
  u += 0x7fffu + ((u >> 16) & 1u);
  return (unsigned short)(u >> 16);
}
struct BfPair { short hi, lo; };
DEVI BfPair split2(float x) {
  unsigned short h = f2bf_rne(x);
  float hf = __uint_as_float(((unsigned)h) << 16);
  BfPair r;
  r.hi = (short)h;
  r.lo = (short)f2bf_rne(x - hf);
  return r;
}

// ---------------------------------------------------------------------------
// f64-MFMA GEMM BODY (R16 verbatim logic; LDS passed in). Tile 64x64, BK=32,
// double-buffered. Probed layout (R12-validated), scalar fp64 fallback.
// Per-accumulator ascending-k chains -> bit-identical to R12-R16.
// ---------------------------------------------------------------------------
template <typename OUTT, bool BTRANS, int BIASMODE>
DEVI void f64_body(float* AsB, float* BsB,
    const float* Ab, const float* Bb, const float* bias, OUTT* Cb,
    int Kd, int lda, int ldb, int ldc, int m0, int n0)
{
  // As(buf,k,m) = AsB[buf*2304 + k*72 + m]
  const int tid = threadIdx.x;
  const int lane = tid & 63, w = tid >> 6;
  const int wr = w >> 1, wc = w & 1;
  const int l15 = lane & 15, l4 = lane >> 4;

  // runtime layout probe (wave-uniform) — R12-validated
  f64x4 zz = {0.0, 0.0, 0.0, 0.0};
  f64x4 p1 = __builtin_amdgcn_mfma_f64_16x16x4f64(1.0, (double)l15, zz, 0, 0, 0);
  f64x4 p2 = __builtin_amdgcn_mfma_f64_16x16x4f64((double)l15, 1.0, zz, 0, 0, 0);
  int a1 = 1, b1 = 1, c1 = 1, a2 = 1, b2 = 1, c2 = 1;
#pragma unroll
  for (int rr = 0; rr < 4; ++rr) {
    a1 &= (p1[rr] == 4.0 * l15);
    b1 &= (p1[rr] == 4.0 * (l4 * 4 + rr));
    c1 &= (p1[rr] == 4.0 * (l4 + 4 * rr));
    a2 &= (p2[rr] == 4.0 * (l4 * 4 + rr));
    b2 &= (p2[rr] == 4.0 * (l4 + 4 * rr));
    c2 &= (p2[rr] == 4.0 * l15);
  }
  a1 = __all(a1); b1 = __all(b1); c1 = __all(c1);
  a2 = __all(a2); b2 = __all(b2); c2 = __all(c2);
  int dmap = 0, useM = 1;
  if      (a1 && a2) dmap = 0;
  else if (a1 && b2) dmap = 1;
  else if (b1 && c2) dmap = 2;
  else if (c1 && c2) dmap = 3;
  else useM = 0;

  f64x4 acc[2][2];
#pragma unroll
  for (int i = 0; i < 2; ++i)
#pragma unroll
    for (int j = 0; j < 2; ++j) acc[i][j] = (f64x4){0.0, 0.0, 0.0, 0.0};

  const int sm = tid >> 2, skf = tid & 3;           // A / B-trans rows
  const int bkl = tid >> 4, bnf = tid & 15;         // B non-trans

  const int nT = Kd >> 5;
  float4 a0_, a1_, b0_, b1_;

  auto LOADT = [&](int k0) {
    a0_ = *(const float4*)(Ab + (size_t)(m0 + sm) * lda + k0 + 4 * skf);
    a1_ = *(const float4*)(Ab + (size_t)(m0 + sm) * lda + k0 + 16 + 4 * skf);
    if (BTRANS) {
      b0_ = *(const float4*)(Bb + (size_t)(n0 + sm) * ldb + k0 + 4 * skf);
      b1_ = *(const float4*)(Bb + (size_t)(n0 + sm) * ldb + k0 + 16 + 4 * skf);
    } else {
      b0_ = *(const float4*)(Bb + (size_t)(k0 + bkl) * ldb + n0 + 4 * bnf);
      b1_ = *(const float4*)(Bb + (size_t)(k0 + 16 + bkl) * ldb + n0 + 4 * bnf);
    }
  };
  auto WRITET = [&](int buf) {
    float* As = AsB + buf * 2304;
    float* Bs = BsB + buf * 2304;
    As[(4 * skf + 0) * 72 + sm] = a0_.x; As[(4 * skf + 1) * 72 + sm] = a0_.y;
    As[(4 * skf + 2) * 72 + sm] = a0_.z; As[(4 * skf + 3) * 72 + sm] = a0_.w;
    As[(16 + 4 * skf + 0) * 72 + sm] = a1_.x; As[(16 + 4 * skf + 1) * 72 + sm] = a1_.y;
    As[(16 + 4 * skf + 2) * 72 + sm] = a1_.z; As[(16 + 4 * skf + 3) * 72 + sm] = a1_.w;
    if (BTRANS) {
      Bs[(4 * skf + 0) * 72 + sm] = b0_.x; Bs[(4 * skf + 1) * 72 + sm] = b0_.y;
      Bs[(4 * skf + 2) * 72 + sm] = b0_.z; Bs[(4 * skf + 3) * 72 + sm] = b0_.w;
      Bs[(16 + 4 * skf + 0) * 72 + sm] = b1_.x; Bs[(16 + 4 * skf + 1) * 72 + sm] = b1_.y;
      Bs[(16 + 4 * skf + 2) * 72 + sm] = b1_.z; Bs[(16 + 4 * skf + 3) * 72 + sm] = b1_.w;
    } else {
      *(float4*)&Bs[bkl * 72 + 4 * bnf] = b0_;
      *(float4*)&Bs[(16 + bkl) * 72 + 4 * bnf] = b1_;
    }
  };

  LOADT(0);
  WRITET(0);
  __syncthreads();

  for (int kt = 0; kt < nT; ++kt) {
    const int cur = kt & 1;
    if (kt + 1 < nT) LOADT((kt + 1) * 32);

    const float* As = AsB + cur * 2304;
    const float* Bs = BsB + cur * 2304;
    if (useM) {
#pragma unroll
      for (int kq = 0; kq < 8; ++kq) {
        int kk = kq * 4 + l4;
        double a0  = (double)As[kk * 72 + wr * 32 + l15];
        double a1v = (double)As[kk * 72 + wr * 32 + 16 + l15];
        double b0  = (double)Bs[kk * 72 + wc * 32 + l15];
        double b1v = (double)Bs[kk * 72 + wc * 32 + 16 + l15];
        acc[0][0] = __builtin_amdgcn_mfma_f64_16x16x4f64(a0,  b0,  acc[0][0], 0, 0, 0);
        acc[0][1] = __builtin_amdgcn_mfma_f64_16x16x4f64(a0,  b1v, acc[0][1], 0, 0, 0);
        acc[1][0] = __builtin_amdgcn_mfma_f64_16x16x4f64(a1v, b0,  acc[1][0], 0, 0, 0);
        acc[1][1] = __builtin_amdgcn_mfma_f64_16x16x4f64(a1v, b1v, acc[1][1], 0, 0, 0);
      }
    } else {
#pragma unroll
      for (int k = 0; k < 32; ++k) {
        double bv0 = (double)Bs[k * 72 + wc * 32 + l15];
        double bv1 = (double)Bs[k * 72 + wc * 32 + 16 + l15];
#pragma unroll
        for (int fr = 0; fr < 2; ++fr)
#pragma unroll
          for (int rr = 0; rr < 4; ++rr) {
            double av = (double)As[k * 72 + wr * 32 + fr * 16 + l4 * 4 + rr];
            acc[fr][0][rr] += av * bv0;
            acc[fr][1][rr] += av * bv1;
          }
      }
    }

    if (kt + 1 < nT) WRITET(cur ^ 1);
    __syncthreads();
  }

  // epilogue (frozen: fp64->fp32 cast, then fp32 bias adds)
#pragma unroll
  for (int fr = 0; fr < 2; ++fr)
#pragma unroll
    for (int fc = 0; fc < 2; ++fc)
#pragma unroll
      for (int rr = 0; rr < 4; ++rr) {
        int ri, ci;
        if (!useM || dmap == 0) { ri = l4 * 4 + rr; ci = l15; }
        else if (dmap == 1)     { ri = l4 + 4 * rr; ci = l15; }
        else if (dmap == 2)     { ri = l15; ci = l4 * 4 + rr; }
        else                    { ri = l15; ci = l4 + 4 * rr; }
        int row = m0 + wr * 32 + fr * 16 + ri;
        int col = n0 + wc * 32 + fc * 16 + ci;
        double v = acc[fr][fc][rr];
        if constexpr (std::is_same<OUTT, double>::value) {
          Cb[(size_t)row * ldc + col] = v;
        } else {
          float s = (float)v;
          float cb = (BIASMODE == 1) ? bias[col] : 0.f;
          float rb = (BIASMODE == 2) ? bias[row] : 0.f;
          ((float*)Cb)[(size_t)row * ldc + col] = s + cb + rb;
        }
      }
}

// ---------------------------------------------------------------------------
// bf16-split value-path GEMM BODY (R16 verbatim logic; LDS passed in).
// Tile 64x64, BK=32, double-buffered, 3-pass split MFMA. Bit-identical to R9.
// Array layout: Xh(buf,idx) = XhB[buf*2048 + idx], idx < 2048.
// ---------------------------------------------------------------------------
template <bool BTRANS, int BIASMODE>
DEVI void bf16_body(short* AhB, short* AlB, short* BhB, short* BlB,
    const float* A, const float* Bz, const float* bias, float* Cz,
    int Kd, int lda, int ldb, int ldc, int m0, int n0)
{
  const int tid = threadIdx.x;
  const int lane = tid & 63, w = tid >> 6;
  const int wr = w >> 1, wc = w & 1;
  const int r16 = lane & 15, kg = lane >> 4;

  f32x4 acc[2][2];
#pragma unroll
  for (int i = 0; i < 2; ++i)
#pragma unroll
    for (int j = 0; j < 2; ++j) acc[i][j] = (f32x4){0.f, 0.f, 0.f, 0.f};

  const int row = tid >> 2, kseg = tid & 3;
  const int gcol = tid & 63, gks = tid >> 6;

  const int nT = Kd >> 5;
  float4 pa0, pa1, pb0, pb1;
  float gb[8];

  auto LOADT = [&](int k0) {
    pa0 = *(const float4*)(A + (size_t)(m0 + row) * lda + k0 + kseg * 8);
    pa1 = *(const float4*)(A + (size_t)(m0 + row) * lda + k0 + kseg * 8 + 4);
    if (BTRANS) {
      pb0 = *(const float4*)(Bz + (size_t)(n0 + row) * ldb + k0 + kseg * 8);
      pb1 = *(const float4*)(Bz + (size_t)(n0 + row) * ldb + k0 + kseg * 8 + 4);
    } else {
#pragma unroll
      for (int j = 0; j < 8; ++j)
        gb[j] = Bz[(size_t)(k0 + gks * 8 + j) * ldb + n0 + gcol];
    }
  };
  auto WRITET = [&](int buf) {
    {
      BfPair q0 = split2(pa0.x), q1 = split2(pa0.y), q2 = split2(pa0.z), q3 = split2(pa0.w);
      BfPair q4 = split2(pa1.x), q5 = split2(pa1.y), q6 = split2(pa1.z), q7 = split2(pa1.w);
      bf16x8 h = {q0.hi, q1.hi, q2.hi, q3.hi, q4.hi, q5.hi, q6.hi, q7.hi};
      bf16x8 l = {q0.lo, q1.lo, q2.lo, q3.lo, q4.lo, q5.lo, q6.lo, q7.lo};
      int idx = (kseg * 64 + row) * 8;
      *(bf16x8*)&AhB[buf * 2048 + idx] = h;
      *(bf16x8*)&AlB[buf * 2048 + idx] = l;
    }
    if (BTRANS) {
      BfPair q0 = split2(pb0.x), q1 = split2(pb0.y), q2 = split2(pb0.z), q3 = split2(pb0.w);
      BfPair q4 = split2(pb1.x), q5 = split2(pb1.y), q6 = split2(pb1.z), q7 = split2(pb1.w);
      bf16x8 h = {q0.hi, q1.hi, q2.hi, q3.hi, q4.hi, q5.hi, q6.hi, q7.hi};
      bf16x8 l = {q0.lo, q1.lo, q2.lo, q3.lo, q4.lo, q5.lo, q6.lo, q7.lo};
      int idx = (kseg * 64 + row) * 8;
      *(bf16x8*)&BhB[buf * 2048 + idx] = h;
      *(bf16x8*)&BlB[buf * 2048 + idx] = l;
    } else {
      short hv[8], lv[8];
#pragma unroll
      for (int j = 0; j < 8; ++j) {
        BfPair p = split2(gb[j]);
        hv[j] = p.hi; lv[j] = p.lo;
      }
      bf16x8 h = {hv[0], hv[1], hv[2], hv[3], hv[4], hv[5], hv[6], hv[7]};
      bf16x8 l = {lv[0], lv[1], lv[2], lv[3], lv[4], lv[5], lv[6], lv[7]};
      int idx = (gks * 64 + gcol) * 8;
      *(bf16x8*)&BhB[buf * 2048 + idx] = h;
      *(bf16x8*)&BlB[buf * 2048 + idx] = l;
    }
  };

  LOADT(0);
  WRITET(0);
  __syncthreads();

  for (int kt = 0; kt < nT; ++kt) {
    const int cur = kt & 1;
    if (kt + 1 < nT) LOADT((kt + 1) * 32);

    bf16x8 ah[2], al[2], bh[2], bl[2];
#pragma unroll
    for (int f = 0; f < 2; ++f) {
      int ia = (kg * 64 + wr * 32 + f * 16 + r16) * 8;
      int ib = (kg * 64 + wc * 32 + f * 16 + r16) * 8;
      ah[f] = *(const bf16x8*)&AhB[cur * 2048 + ia];
      al[f] = *(const bf16x8*)&AlB[cur * 2048 + ia];
      bh[f] = *(const bf16x8*)&BhB[cur * 2048 + ib];
      bl[f] = *(const bf16x8*)&BlB[cur * 2048 + ib];
    }
#pragma unroll
    for (int fr = 0; fr < 2; ++fr)
#pragma unroll
      for (int fc = 0; fc < 2; ++fc) {
        f32x4 c = acc[fr][fc];
        c = __builtin_amdgcn_mfma_f32_16x16x32_bf16(al[fr], bh[fc], c, 0, 0, 0);
        c = __builtin_amdgcn_mfma_f32_16x16x32_bf16(ah[fr], bl[fc], c, 0, 0, 0);
        c = __builtin_amdgcn_mfma_f32_16x16x32_bf16(ah[fr], bh[fc], c, 0, 0, 0);
        acc[fr][fc] = c;
      }

    if (kt + 1 < nT) WRITET(cur ^ 1);
    __syncthreads();
  }

#pragma unroll
  for (int fr = 0; fr < 2; ++fr)
#pragma unroll
    for (int fc = 0; fc < 2; ++fc) {
      int col = n0 + wc * 32 + fc * 16 + r16;
      float cb = (BIASMODE == 1) ? bias[col] : 0.f;
#pragma unroll
      for (int rr = 0; rr < 4; ++rr) {
        int rw = m0 + wr * 32 + fr * 16 + kg * 4 + rr;
        float rb = (BIASMODE == 2) ? bias[rw] : 0.f;
        Cz[(size_t)rw * ldc + col] = acc[fr][fc][rr] + cb + rb;
      }
    }
}

// ---------------------------------------------------------------------------
// Fused projections: z=0 -> Q (f64), z=1 -> K (f64), z=2 -> V (bf16).
// LDS union: S1/S2 (18,432B each) host both the f64 [2][32][72] planes and
// the bf16 hi/lo pairs (2 x 4KB shorts each).
// ---------------------------------------------------------------------------
__global__ __launch_bounds__(256) void projQKV_k(
    const float* __restrict__ x,
    const float* __restrict__ Wq, const float* __restrict__ Wk,
    const float* __restrict__ Wv,
    const float* __restrict__ bq, const float* __restrict__ bk,
    const float* __restrict__ bv,
    float* __restrict__ Q, float* __restrict__ Kf, float* __restrict__ Vf)
{
  __shared__ __align__(16) float S1[2 * 2304];
  __shared__ __align__(16) float S2[2 * 2304];
  const int m0 = blockIdx.y * 64, n0 = blockIdx.x * 64;
  if (blockIdx.z < 2) {
    const float* W = blockIdx.z ? Wk : Wq;
    const float* b = blockIdx.z ? bk : bq;
    float* C = blockIdx.z ? Kf : Q;
    f64_body<float, true, 1>(S1, S2, x, W, b, C, 1024, 1024, 1024, 1024, m0, n0);
  } else {
    bf16_body<true, 1>((short*)S1, (short*)S1 + 4096,
                       (short*)S2, (short*)S2 + 4096,
                       x, Wv, bv, Vf, 1024, 1024, 1024, 1024, m0, n0);
  }
}

// Fused compress: z=0,1 -> Kc batches (f64); z=2,3 -> Vc batches (bf16).
__global__ __launch_bounds__(256) void compKV_k(
    const float* __restrict__ Wc, const float* __restrict__ Kf,
    const float* __restrict__ Vf, const float* __restrict__ bc,
    float* __restrict__ Kc, float* __restrict__ Vc)
{
  __shared__ __align__(16) float S1[2 * 2304];
  __shared__ __align__(16) float S2[2 * 2304];
  const int m0 = blockIdx.y * 64, n0 = blockIdx.x * 64;
  const size_t M1 = (size_t)1024 * 1024;
  if (blockIdx.z < 2) {
    f64_body<float, false, 2>(S1, S2, Wc, Kf + blockIdx.z * M1, bc,
                              Kc + blockIdx.z * M1, 1024, 1024, 1024, 1024, m0, n0);
  } else {
    int zb = blockIdx.z - 2;
    bf16_body<false, 2>((short*)S1, (short*)S1 + 4096,
                        (short*)S2, (short*)S2 + 4096,
                        Wc, Vf + zb * M1, bc, Vc + zb * M1,
                        1024, 1024, 1024, 1024, m0, n0);
  }
}

// Dot planes (f64 SIM): z = group slot; pair = group_base + z.
__global__ __launch_bounds__(256) void dotsim_k(
    const float* __restrict__ Q, const float* __restrict__ Kc,
    double* __restrict__ dotp, int group_base)
{
  __shared__ __align__(16) float S1[2 * 2304];
  __shared__ __align__(16) float S2[2 * 2304];
  const int m0 = blockIdx.y * 64, n0 = blockIdx.x * 64;
  int pair = group_base + (int)blockIdx.z;
  int bb = pair >> 4, hh = pair & 15;
  const float* Ab = Q + ((size_t)bb * Tn) * 1024 + (size_t)hh * 64;
  const float* Bb = Kc + ((size_t)bb * Cn) * 1024 + (size_t)hh * 64;
  double* Cb = dotp + (size_t)blockIdx.z * Tn * Cn;
  f64_body<double, true, 0>(S1, S2, Ab, Bb, nullptr, Cb, 64, 1024, 1024, 1024, m0, n0);
}

// Output projection (bf16, standalone).
__global__ __launch_bounds__(256) void wo_k(
    const float* __restrict__ at, const float* __restrict__ Wo,
    const float* __restrict__ bo, float* __restrict__ out)
{
  __shared__ __align__(16) float S1[2 * 2304];
  __shared__ __align__(16) float S2[2 * 2304];
  const int m0 = blockIdx.y * 64, n0 = blockIdx.x * 64;
  bf16_body<true, 1>((short*)S1, (short*)S1 + 4096,
                     (short*)S2, (short*)S2 + 4096,
                     at, Wo, bo, out, 1024, 1024, 1024, 1024, m0, n0);
}

// kn[b*16+h][c] = 1 / max(||Kc[b, c, h*64 : +64]||, 1e-12)   (fp64)
__global__ __launch_bounds__(256) void kn_k2(const float* __restrict__ Kc,
                                             double* __restrict__ kn)
{
  int idx = (int)blockIdx.x * 256 + (int)threadIdx.x;
  int c = idx & 1023;
  int p = idx >> 10;
  int b = p >> 4, h = p & 15;
  const float* row = Kc + ((size_t)(b * 1024 + c)) * 1024 + h * 64;
  double s = 0.0;
  for (int d = 0; d < 64; ++d) { double v = (double)row[d]; s += v * v; }
  kn[(size_t)p * 1024 + c] = 1.0 / fmax(sqrt(s), 1e-12);
}

// Fused exact top-64 + softmax + PV (bit-frozen, R5-validated).
__global__ __launch_bounds__(256) void topk_attn_k(
    const double* __restrict__ dotb, const double* __restrict__ kn,
    const float* __restrict__ Vc, float* __restrict__ attnout, int group_base)
{
  __shared__ int sC[4][64];
  __shared__ float sD[4][64];

  const int lane = threadIdx.x & 63, wv = threadIdx.x >> 6;
  const int g = (int)blockIdx.x >> 8;
  const int t = ((int)blockIdx.x & 255) * 4 + wv;
  const int pair = group_base + g;
  const int bb = pair >> 4, hh = pair & 15;

  const double* drow = dotb + ((size_t)g * Tn + t) * (size_t)Cn;
  const double* knr  = kn + ((size_t)(bb * Hn + hh)) * Cn;

  double dv[16];
  unsigned long long u[16];
#pragma unroll
  for (int j = 0; j < 8; ++j) {
    double2 dd = *(const double2*)(drow + j * 128 + 2 * lane);
    double2 kk = *(const double2*)(knr  + j * 128 + 2 * lane);
    dv[2 * j] = dd.x; dv[2 * j + 1] = dd.y;
    u[2 * j]     = mapd(dd.x * kk.x);
    u[2 * j + 1] = mapd(dd.y * kk.y);
  }
  unsigned hi[16];
#pragma unroll
  for (int i = 0; i < 16; ++i) hi[i] = (unsigned)(u[i] >> 32);

  unsigned TH = 0;
  for (int bit = 31; bit >= 0; --bit) {
    unsigned Tc = TH | (1u << bit);
    int c = 0;
#pragma unroll
    for (int i = 0; i < 16; ++i) c += (hi[i] >= Tc);
    if (wsumi(c) >= 64) TH = Tc;
  }
  int mhi = 0;
#pragma unroll
  for (int i = 0; i < 16; ++i) mhi += (hi[i] > TH);
  mhi = wsumi(mhi);
  const int need1 = 64 - mhi;
  unsigned TL = 0;
  for (int bit = 31; bit >= 0; --bit) {
    unsigned Tc = TL | (1u << bit);
    int c = 0;
#pragma unroll
    for (int i = 0; i < 16; ++i) c += (hi[i] == TH && (unsigned)u[i] >= Tc);
    if (wsumi(c) >= need1) TL = Tc;
  }
  const unsigned long long V64 = ((unsigned long long)TH << 32) | TL;

  int base = 0;
#pragma unroll
  for (int i = 0; i < 16; ++i) {
    const int cix = 128 * (i >> 1) + 2 * lane + (i & 1);
    bool sel = (u[i] > V64);
    unsigned long long mk = __ballot(sel);
    if (sel) {
      int r = __popcll(mk & ((1ull << lane) - 1ull));
      sC[wv][base + r] = cix;
      sD[wv][base + r] = (float)dv[i];
    }
    base += __popcll(mk);
  }
  const int need = 64 - base;
  unsigned taken = 0;
  for (int r = 0; r < need; ++r) {
    int mn = 0x7fffffff;
#pragma unroll
    for (int i = 0; i < 16; ++i) {
      int cix = 128 * (i >> 1) + 2 * lane + (i & 1);
      if (u[i] == V64 && !((taken >> i) & 1u)) mn = mn < cix ? mn : cix;
    }
    mn = wmini(mn);
#pragma unroll
    for (int i = 0; i < 16; ++i) {
      int cix = 128 * (i >> 1) + 2 * lane + (i & 1);
      if (u[i] == V64 && !((taken >> i) & 1u) && cix == mn) {
        taken |= 1u << i;
        sC[wv][base + r] = mn;
        sD[wv][base + r] = (float)dv[i];
      }
    }
  }
  __syncthreads();

  int ck = sC[wv][lane];
  float sc = sD[wv][lane] * 0.125f;
  float mx = wfmax(sc);
  float w = expf(sc - mx);
  float sw = wfsum(w);
  w /= sw;

  const float* Vb = Vc + (size_t)bb * ((size_t)Cn * 1024) + hh * 64 + lane;
  float acc = 0.f;
#pragma unroll 4
  for (int k = 0; k < 64; ++k) {
    int c = __shfl(ck, k);
    float wk = __shfl(w, k);
    acc = fmaf(wk, Vb[(size_t)c * 1024], acc);
  }
  attnout[((size_t)(bb * Tn + t)) * 1024 + hh * 64 + lane] = acc;
}

// ---------------------------------------------------------------------------
extern "C" void kernel_launch(void* const* d_in, const int* in_sizes, int n_in,
                              void* d_out, int out_size, void* d_ws, size_t ws_size,
                              hipStream_t stream)
{
  const float* x  = (const float*)d_in[0];
  const float* Wq = (const float*)d_in[1];
  const float* bq = (const float*)d_in[2];
  const float* Wk = (const float*)d_in[3];
  const float* bk = (const float*)d_in[4];
  const float* Wv = (const float*)d_in[5];
  const float* bv = (const float*)d_in[6];
  const float* Wo = (const float*)d_in[7];
  const float* bo = (const float*)d_in[8];
  const float* Wc = (const float*)d_in[9];
  const float* bc = (const float*)d_in[10];
  float* out = (float*)d_out;

  const size_t NE = (size_t)2048 * 1024;
  float* Q   = (float*)d_ws;
  float* Kf  = Q + NE;
  float* Vf  = Kf + NE;
  float* Kc  = Vf + NE;
  float* Vc  = Kc + NE;
  float* at  = Vc + NE;
  double* kn = (double*)(at + NE);
  double* tail = kn + 32768;

  const size_t fixedB = 6 * NE * 4 + 32768 * 8;
  const size_t dotPairB = (size_t)Tn * Cn * 8;   // 8 MiB per (b,h) pair
  if (ws_size < fixedB) return;

  size_t rem = ws_size - fixedB;
  double* dotp; int G;
  if      (rem >= 32 * dotPairB) { G = 32; dotp = tail; }
  else if (rem >= 16 * dotPairB) { G = 16; dotp = tail; }
  else if (rem >=  8 * dotPairB) { G = 8;  dotp = tail; }
  else if (rem >=  4 * dotPairB) { G = 4;  dotp = tail; }
  else if (rem >=  2 * dotPairB) { G = 2;  dotp = tail; }
  else { G = 2; dotp = (double*)Kf; }  // Kf+Vf dead by then (16 MiB)

  dim3 blk(256, 1, 1);

  // Fused Q/K (f64) + V (bf16) projections in one dispatch
  projQKV_k<<<dim3(16, 32, 3), blk, 0, stream>>>(
      x, Wq, Wk, Wv, bq, bk, bv, Q, Kf, Vf);

  // Fused Kc (f64, z=0,1) + Vc (bf16, z=2,3) compress
  compKV_k<<<dim3(16, 16, 4), blk, 0, stream>>>(Wc, Kf, Vf, bc, Kc, Vc);

  kn_k2<<<dim3(128), blk, 0, stream>>>(Kc, kn);

  // Dot planes (f64 SIM) + fused topk/softmax/PV
  for (int gb = 0; gb < 32; gb += G) {
    dotsim_k<<<dim3(16, 16, G), blk, 0, stream>>>(Q, Kc, dotp, gb);
    topk_attn_k<<<dim3(256 * G), blk, 0, stream>>>(dotp, kn, Vc, at, gb);
  }

  // Output projection (bf16)
  wo_k<<<dim3(16, 32, 1), blk, 0, stream>>>(at, Wo, bo, out);
}